// Round 6
// baseline (247.741 us; speedup 1.0000x reference)
//
#include <hip/hip_runtime.h>
#include <math.h>

#define B_ 2
#define T_ 2048
#define C_ 1024
#define H_ 16
#define D_ 64

typedef unsigned short u16;
typedef unsigned int u32;
typedef __bf16 bf16x8 __attribute__((ext_vector_type(8)));
typedef _Float16 f16x8 __attribute__((ext_vector_type(8)));
typedef __fp16 fp16x2 __attribute__((ext_vector_type(2)));
typedef float f32x4 __attribute__((ext_vector_type(4)));
typedef u16 u16x4 __attribute__((ext_vector_type(4)));

__device__ __forceinline__ u16 f2bf(float f) {
    union { float f; u32 u; } v; v.f = f;
    u32 r = v.u + 0x7fffu + ((v.u >> 16) & 1u);   // RNE
    return (u16)(r >> 16);
}

#define GLD_LDS(g, l) \
    __builtin_amdgcn_global_load_lds( \
        (const __attribute__((address_space(1))) u32*)(const void*)(g), \
        (__attribute__((address_space(3))) u32*)(void*)(l), 16, 0, 0)

// ---------------------------------------------------------------------------
// cast fp32 -> bf16
// ---------------------------------------------------------------------------
__global__ __launch_bounds__(256) void cast_bf16(const float* __restrict__ in,
                                                 u16* __restrict__ out) {
    const int i = (blockIdx.x * 256 + threadIdx.x) * 4;
    float4 v = *(const float4*)(in + i);
    u16x4 o;
    o.x = f2bf(v.x); o.y = f2bf(v.y); o.z = f2bf(v.z); o.w = f2bf(v.w);
    *(u16x4*)(out + i) = o;
}

// ---------------------------------------------------------------------------
// QKV^T GEMM, fused RoPE + per-head split, LDS-bounce epilogue.
// Out[3C][Ntok] = w_qkv @ x^T. C/D: row = qkv-dim (4 consecutive d / lane),
// col = token. Epilogue stages the 128x128 tile in LDS ([t][d] for q/k after
// RoPE, [d][t] for V) then writes global fully coalesced (16B stores).
// Staging chunks remapped to [kq][row][8] so frag reads are 2-way not 8-way.
// ---------------------------------------------------------------------------
__global__ __launch_bounds__(256) void gemm_qkv(const u16* __restrict__ A,
                                                const u16* __restrict__ Bm,
                                                u16* __restrict__ qb,
                                                u16* __restrict__ kb,
                                                u16* __restrict__ vt) {
    const int K = C_;
    __shared__ union {
        struct { u16 As[4096]; u16 Bs[4096]; } s;
        u16 Et[128 * 136];
    } L;
    const int tid = threadIdx.x;
    const int lane = tid & 63;
    const int wave = tid >> 6;
    const int wm = (wave >> 1) * 64;
    const int wn = (wave & 1) * 64;
    const int m0 = blockIdx.y * 128;   // over 3C
    const int n0 = blockIdx.x * 128;   // over tokens

    const int srow = lane & 15;          // row within 16-row chunk
    const int skq = (lane >> 4) * 8;     // k-offset within BK=32
    const u16* gA0 = A + (size_t)(m0 + wave * 16 + srow) * K + skq;
    const u16* gA1 = A + (size_t)(m0 + 64 + wave * 16 + srow) * K + skq;
    const u16* gB0 = Bm + (size_t)(n0 + wave * 16 + srow) * K + skq;
    const u16* gB1 = Bm + (size_t)(n0 + 64 + wave * 16 + srow) * K + skq;
    u16* lA0 = L.s.As + wave * 512;
    u16* lA1 = L.s.As + (4 + wave) * 512;
    u16* lB0 = L.s.Bs + wave * 512;
    u16* lB1 = L.s.Bs + (4 + wave) * 512;

    f32x4 acc[4][4] = {};
    const int col = lane & 15;
    const int quad = lane >> 4;
    const int fin = quad * 128 + col * 8;   // intra-chunk frag offset

    for (int k0 = 0; k0 < K; k0 += 32) {
        __syncthreads();
        GLD_LDS(gA0 + k0, lA0);
        GLD_LDS(gA1 + k0, lA1);
        GLD_LDS(gB0 + k0, lB0);
        GLD_LDS(gB1 + k0, lB1);
        __syncthreads();
        bf16x8 a[4], b[4];
        #pragma unroll
        for (int i = 0; i < 4; ++i)
            a[i] = *(const bf16x8*)(L.s.As + (wm + i * 16) * 32 + fin);
        #pragma unroll
        for (int j = 0; j < 4; ++j)
            b[j] = *(const bf16x8*)(L.s.Bs + (wn + j * 16) * 32 + fin);
        #pragma unroll
        for (int i = 0; i < 4; ++i)
            #pragma unroll
            for (int j = 0; j < 4; ++j)
                acc[i][j] = __builtin_amdgcn_mfma_f32_16x16x32_bf16(
                    a[i], b[j], acc[i][j], 0, 0, 0);
    }

    const int rq = quad * 4;
    const int sslot = m0 >> 10;   // 0=q 1=k 2=v, block-uniform
    __syncthreads();              // main-loop LDS reads done in all waves

    if (sslot < 2) {
        // RoPE in-register, stage Et[token][d-within-tile]
        #pragma unroll
        for (int i = 0; i < 4; ++i) {
            const int mloc = wm + i * 16 + rq;
            const int dbase = (m0 + mloc) & 63;
            #pragma unroll
            for (int j = 0; j < 4; ++j) {
                const int nloc = wn + j * 16 + col;
                const int t = (n0 + nloc) & (T_ - 1);
                const float tf = (float)t;
                u16x4 ov;
                #pragma unroll
                for (int p = 0; p < 2; ++p) {
                    const float ip = (float)((dbase >> 1) + p);
                    const float theta = __expf(-0.2878231366f * ip); // 1e4^(-ip/32)
                    const float ang = tf * theta;
                    float sn, cs; __sincosf(ang, &sn, &cs);
                    const float x0 = acc[i][j][2 * p];
                    const float x1 = acc[i][j][2 * p + 1];
                    ov[2 * p]     = f2bf(x0 * cs - x1 * sn);
                    ov[2 * p + 1] = f2bf(x1 * cs + x0 * sn);
                }
                *(u16x4*)(L.Et + nloc * 136 + mloc) = ov;
            }
        }
    } else {
        // V: f16 convert, stage transposed Et[d-within-tile][token]
        #pragma unroll
        for (int i = 0; i < 4; ++i) {
            const int mloc = wm + i * 16 + rq;
            #pragma unroll
            for (int j = 0; j < 4; ++j) {
                const int nloc = wn + j * 16 + col;
                #pragma unroll
                for (int r = 0; r < 4; ++r) {
                    union { _Float16 h; u16 u; } cv;
                    cv.h = (_Float16)acc[i][j][r];
                    L.Et[(mloc + r) * 136 + nloc] = cv.u;
                }
            }
        }
    }
    __syncthreads();

    if (sslot < 2) {
        u16* dstb = (sslot == 0) ? qb : kb;
        #pragma unroll
        for (int s = 0; s < 8; ++s) {
            const int idx = s * 256 + tid;
            const int chunk = idx & 7;          // 16B d-chunk
            const int tloc = (idx >> 3) & 127;
            const int half = idx >> 10;         // head half of the tile
            const uint4 v =
                *(const uint4*)(L.Et + tloc * 136 + half * 64 + chunk * 8);
            const int gt = n0 + tloc;
            const int bb = gt >> 11;
            const int tt = gt & (T_ - 1);
            const int hh = ((m0 >> 6) & 15) + half;
            *(uint4*)(dstb + ((size_t)(bb * H_ + hh) * T_ + tt) * D_ +
                      chunk * 8) = v;
        }
    } else {
        const int bb = n0 >> 11;
        const int tt0 = n0 & (T_ - 1);
        #pragma unroll
        for (int s = 0; s < 8; ++s) {
            const int idx = s * 256 + tid;
            const int tc = idx & 15;            // 16B t-chunk
            const int dloc = idx >> 4;          // 0..127
            const uint4 v = *(const uint4*)(L.Et + dloc * 136 + tc * 8);
            const int hh = ((m0 >> 6) & 15) + (dloc >> 6);
            const int d = dloc & 63;
            *(uint4*)(vt + ((size_t)(bb * H_ + hh) * D_ + d) * T_ + tt0 +
                      tc * 8) = v;
        }
    }
}

// ---------------------------------------------------------------------------
// Plain bf16 GEMM, fp32 output: Out = A @ Bm^T (remapped staging).
// ---------------------------------------------------------------------------
__global__ __launch_bounds__(256) void gemm_bt(const u16* __restrict__ A,
                                               const u16* __restrict__ Bm,
                                               float* __restrict__ OutF,
                                               int M, int N, int K) {
    __shared__ u16 As[128 * 32];
    __shared__ u16 Bs[128 * 32];
    const int tid = threadIdx.x;
    const int lane = tid & 63;
    const int wave = tid >> 6;
    const int wm = (wave >> 1) * 64;
    const int wn = (wave & 1) * 64;
    const int m0 = blockIdx.y * 128;
    const int n0 = blockIdx.x * 128;

    const int srow = lane & 15;
    const int skq = (lane >> 4) * 8;
    const u16* gA0 = A + (size_t)(m0 + wave * 16 + srow) * K + skq;
    const u16* gA1 = A + (size_t)(m0 + 64 + wave * 16 + srow) * K + skq;
    const u16* gB0 = Bm + (size_t)(n0 + wave * 16 + srow) * K + skq;
    const u16* gB1 = Bm + (size_t)(n0 + 64 + wave * 16 + srow) * K + skq;
    u16* lA0 = As + wave * 512;
    u16* lA1 = As + (4 + wave) * 512;
    u16* lB0 = Bs + wave * 512;
    u16* lB1 = Bs + (4 + wave) * 512;

    f32x4 acc[4][4] = {};
    const int col = lane & 15;
    const int quad = lane >> 4;
    const int fin = quad * 128 + col * 8;

    for (int k0 = 0; k0 < K; k0 += 32) {
        __syncthreads();
        GLD_LDS(gA0 + k0, lA0);
        GLD_LDS(gA1 + k0, lA1);
        GLD_LDS(gB0 + k0, lB0);
        GLD_LDS(gB1 + k0, lB1);
        __syncthreads();
        bf16x8 a[4], b[4];
        #pragma unroll
        for (int i = 0; i < 4; ++i)
            a[i] = *(const bf16x8*)(As + (wm + i * 16) * 32 + fin);
        #pragma unroll
        for (int j = 0; j < 4; ++j)
            b[j] = *(const bf16x8*)(Bs + (wn + j * 16) * 32 + fin);
        #pragma unroll
        for (int i = 0; i < 4; ++i)
            #pragma unroll
            for (int j = 0; j < 4; ++j)
                acc[i][j] = __builtin_amdgcn_mfma_f32_16x16x32_bf16(
                    a[i], b[j], acc[i][j], 0, 0, 0);
    }

    const int rq = quad * 4;
    #pragma unroll
    for (int i = 0; i < 4; ++i)
        #pragma unroll
        for (int j = 0; j < 4; ++j)
            #pragma unroll
            for (int r = 0; r < 4; ++r)
                OutF[(size_t)(m0 + wm + i * 16 + rq + r) * N +
                     n0 + wn + j * 16 + col] = acc[i][j][r];
}

// ---------------------------------------------------------------------------
// Flash attention v3: 256 thr / 4 waves / 16 q-rows per wave (64 q per block),
// 64-key chunks. S^T via mfma(K, Q); P f16 packed; no online max.
// K/V staged via GLD with [kq][row][8] chunk layout (2-way banks).
// ---------------------------------------------------------------------------
__global__ __launch_bounds__(256) void attn_mfma(const u16* __restrict__ qb,
                                                 const u16* __restrict__ kb,
                                                 const u16* __restrict__ vtg,
                                                 u16* __restrict__ y) {
    __shared__ u16 Ks[8 * 512];     // chunk (ks*4+n): key n*16+(l&15), d ks*32+(l>>4)*8
    __shared__ u16 Vt[8 * 512];     // chunk (ks*4+n): d n*16+(l&15), key ks*32+(l>>4)*8
    __shared__ u16 Ps[4][16 * 72];  // per-wave P [16 q][64 key] f16
    const int b = blockIdx.z, h = blockIdx.y;
    const int bh = b * H_ + h;
    const int qt = gridDim.x - 1 - blockIdx.x;  // heavy tiles first
    const int q0 = qt * 64;
    const int tid = threadIdx.x;
    const int lane = tid & 63;
    const int wave = tid >> 6;       // 0..3, owns q rows q0+wave*16..+15
    const int col = lane & 15;
    const int quad = lane >> 4;

    // Q B-fragments: lane holds Q[q=col][d=ks*32+quad*8+j]
    const u16* qbase = qb + ((size_t)bh * T_ + q0 + wave * 16) * D_;
    bf16x8 qf[2];
    #pragma unroll
    for (int ks = 0; ks < 2; ++ks)
        qf[ks] = *(const bf16x8*)(qbase + col * D_ + ks * 32 + quad * 8);

    f32x4 o[4] = {};
    float lsum = 0.0f;

    // staging: wave w loads K chunks (n=w, ks=0/1) and V chunks (nd=w, ks=0/1)
    const int sr = lane & 15;
    const int sq8 = (lane >> 4) * 8;
    const u16* kg0 = kb + ((size_t)bh * T_ + wave * 16 + sr) * D_ + sq8;
    const u16* kg1 = kg0 + 32;
    const u16* vg0 = vtg + ((size_t)bh * D_ + wave * 16 + sr) * T_ + sq8;
    const u16* vg1 = vg0 + 32;
    u16* lk0 = Ks + wave * 512;
    u16* lk1 = Ks + (4 + wave) * 512;
    u16* lv0 = Vt + wave * 512;
    u16* lv1 = Vt + (4 + wave) * 512;
    u16* Pw = &Ps[wave][0];

    const int qrow = q0 + wave * 16 + col;
    const int nchunks = qt + 1;
    for (int ci = 0; ci < nchunks; ++ci) {
        const int j0 = ci * 64;
        __syncthreads();   // prior chunk's Ks/Vt reads done
        GLD_LDS(kg0 + (size_t)j0 * D_, lk0);
        GLD_LDS(kg1 + (size_t)j0 * D_, lk1);
        GLD_LDS(vg0 + j0, lv0);
        GLD_LDS(vg1 + j0, lv1);
        __syncthreads();   // DMA drained

        // S^T = K Q^T : A = K (m=key), B = Q (n=q)
        f32x4 s[4] = {};
        #pragma unroll
        for (int ks = 0; ks < 2; ++ks) {
            #pragma unroll
            for (int n = 0; n < 4; ++n) {
                const bf16x8 kf = *(const bf16x8*)(Ks + (ks * 4 + n) * 512 +
                                                   quad * 128 + col * 8);
                s[n] = __builtin_amdgcn_mfma_f32_16x16x32_bf16(
                    kf, qf[ks], s[n], 0, 0, 0);
            }
        }

        // exp + packed f16 P store; lane covers keys n*16+quad*4+{0..3}, q=col
        const bool diag = (ci == nchunks - 1);
        #pragma unroll
        for (int n = 0; n < 4; ++n) {
            float p[4];
            #pragma unroll
            for (int r = 0; r < 4; ++r) {
                const float xv = s[n][r] * 0.1803368801f;  // (1/8)*log2(e)
                float pv = __builtin_amdgcn_exp2f(fminf(xv, 80.0f));
                if (diag && (j0 + n * 16 + quad * 4 + r > qrow)) pv = 0.0f;
                p[r] = pv;
                lsum += pv;
            }
            union { fp16x2 h[2]; u32 u[2]; } pk;
            pk.h[0] = __builtin_amdgcn_cvt_pkrtz(p[0], p[1]);
            pk.h[1] = __builtin_amdgcn_cvt_pkrtz(p[2], p[3]);
            *(uint2*)(Pw + col * 72 + n * 16 + quad * 4) =
                make_uint2(pk.u[0], pk.u[1]);
        }

        // O += P V : A = P (m=q), B = V (n=d)
        #pragma unroll
        for (int ks = 0; ks < 2; ++ks) {
            const f16x8 pf = *(const f16x8*)(Pw + col * 72 + ks * 32 + quad * 8);
            #pragma unroll
            for (int n = 0; n < 4; ++n) {
                const f16x8 vf = *(const f16x8*)(Vt + (ks * 4 + n) * 512 +
                                                 quad * 128 + col * 8);
                o[n] = __builtin_amdgcn_mfma_f32_16x16x32_f16(
                    pf, vf, o[n], 0, 0, 0);
            }
        }
    }

    // row-sum for q=col (sum the 4 quads), then lane-transpose to rows
    lsum += __shfl_xor(lsum, 16);
    lsum += __shfl_xor(lsum, 32);
    const float inv = 1.0f / lsum;
    float invr[4];
    #pragma unroll
    for (int r = 0; r < 4; ++r)
        invr[r] = __shfl(inv, quad * 4 + r);   // inv for q = quad*4+r

    #pragma unroll
    for (int r = 0; r < 4; ++r) {
        const int row = q0 + wave * 16 + quad * 4 + r;
        u16* yp = y + (size_t)(b * T_ + row) * C_ + h * D_;
        #pragma unroll
        for (int n = 0; n < 4; ++n)
            yp[n * 16 + col] = f2bf(o[n][r] * invr[r]);
    }
}

// ---------------------------------------------------------------------------
// Launch
// ---------------------------------------------------------------------------
extern "C" void kernel_launch(void* const* d_in, const int* in_sizes, int n_in,
                              void* d_out, int out_size, void* d_ws, size_t ws_size,
                              hipStream_t stream) {
    const float* x      = (const float*)d_in[0];
    const float* w_qkv  = (const float*)d_in[1];
    const float* w_proj = (const float*)d_in[2];
    float* out = (float*)d_out;

    const int M = B_ * T_;                   // 4096
    const size_t nx = (size_t)M * C_;        // 4.19M
    const size_t nwq = (size_t)3 * C_ * C_;
    const size_t nwp = (size_t)C_ * C_;

    u16* xb  = (u16*)d_ws;
    u16* wqb = xb + nx;
    u16* wpb = wqb + nwq;
    u16* qb  = wpb + nwp;
    u16* kb  = qb + nx;
    u16* vt  = kb + nx;      // f16 (b,h,d,t)
    u16* yb  = vt + nx;      // bf16 (b,t,h,d)

    cast_bf16<<<nx / 1024, 256, 0, stream>>>(x, xb);
    cast_bf16<<<nwq / 1024, 256, 0, stream>>>(w_qkv, wqb);
    cast_bf16<<<nwp / 1024, 256, 0, stream>>>(w_proj, wpb);

    // qkv^T = w_qkv @ x^T, fused RoPE + split into qb/kb (bf16) and vt (f16)
    gemm_qkv<<<dim3(M / 128, 3 * C_ / 128), 256, 0, stream>>>(
        wqb, xb, qb, kb, vt);

    attn_mfma<<<dim3(T_ / 64, H_, B_), 256, 0, stream>>>(qb, kb, vt, yb);

    // out = y @ w_proj^T -> fp32
    gemm_bt<<<dim3(C_ / 128, M / 128), 256, 0, stream>>>(
        yb, wpb, out, M, C_, C_);
}

// Round 7
// 206.802 us; speedup vs baseline: 1.1980x; 1.1980x over previous
//
#include <hip/hip_runtime.h>
#include <math.h>

#define B_ 2
#define T_ 2048
#define C_ 1024
#define H_ 16
#define D_ 64
#define NX_ 4194304
#define NWQ_ 3145728
#define NWP_ 1048576

typedef unsigned short u16;
typedef unsigned int u32;
typedef __bf16 bf16x8 __attribute__((ext_vector_type(8)));
typedef _Float16 f16x8 __attribute__((ext_vector_type(8)));
typedef __fp16 fp16x2 __attribute__((ext_vector_type(2)));
typedef float f32x4 __attribute__((ext_vector_type(4)));
typedef u16 u16x4 __attribute__((ext_vector_type(4)));

__device__ __forceinline__ u16 f2bf(float f) {
    union { float f; u32 u; } v; v.f = f;
    u32 r = v.u + 0x7fffu + ((v.u >> 16) & 1u);   // RNE
    return (u16)(r >> 16);
}

#define GLD_LDS(g, l) \
    __builtin_amdgcn_global_load_lds( \
        (const __attribute__((address_space(1))) u32*)(const void*)(g), \
        (__attribute__((address_space(3))) u32*)(void*)(l), 16, 0, 0)

// ---------------------------------------------------------------------------
// fused cast of all three fp32 inputs -> one contiguous bf16 region
// ---------------------------------------------------------------------------
__global__ __launch_bounds__(256) void cast_all(const float* __restrict__ x,
                                                const float* __restrict__ wq,
                                                const float* __restrict__ wp,
                                                u16* __restrict__ out) {
    const int i = (blockIdx.x * 256 + threadIdx.x) * 4;
    const float* src;
    int off;
    if (i < NX_) { src = x; off = i; }
    else if (i < NX_ + NWQ_) { src = wq; off = i - NX_; }
    else { src = wp; off = i - NX_ - NWQ_; }
    float4 v = *(const float4*)(src + off);
    u16x4 o;
    o.x = f2bf(v.x); o.y = f2bf(v.y); o.z = f2bf(v.z); o.w = f2bf(v.w);
    *(u16x4*)(out + i) = o;
}

// ---------------------------------------------------------------------------
// bf16 GEMM, 128x128 tile, BK=64, XOR-swizzled LDS (coalesced GLD +
// conflict-free frag reads). Out = A[M][K] @ Bm[N][K]^T.
// EPI 0: fp32 row-major output. EPI 1: fused RoPE + per-head q/k/v split
// (C/D row = qkv-dim, col = token; 4 consecutive d per lane).
// ---------------------------------------------------------------------------
template <int EPI>
__global__ __launch_bounds__(256) void gemm64(const u16* __restrict__ A,
                                              const u16* __restrict__ Bm,
                                              float* __restrict__ OutF,
                                              u16* __restrict__ qb,
                                              u16* __restrict__ kb,
                                              u16* __restrict__ vt,
                                              int M, int N, int K) {
    __shared__ u16 As[128 * 64];
    __shared__ u16 Bs[128 * 64];
    const int tid = threadIdx.x;
    const int lane = tid & 63;
    const int wave = tid >> 6;
    const int wm = (wave >> 1) * 64;
    const int wn = (wave & 1) * 64;
    const int m0 = blockIdx.y * 128;
    const int n0 = blockIdx.x * 128;

    // staging: chunk = 8 consecutive rows x 64 k (1KB). lane i fetches
    // 16B group ((i&7)^(i>>3)) of row (i>>3) -> contiguous 128B per row,
    // LDS image XOR-swizzled.
    const int rl = lane >> 3;
    const int sg = ((lane & 7) ^ rl) * 8;
    const u16* gA[4]; const u16* gB[4];
    u16 *lA[4], *lB[4];
    #pragma unroll
    for (int c = 0; c < 4; ++c) {
        const int ca = wave * 4 + c;
        gA[c] = A + (size_t)(m0 + ca * 8 + rl) * K + sg;
        gB[c] = Bm + (size_t)(n0 + ca * 8 + rl) * K + sg;
        lA[c] = As + ca * 512;
        lB[c] = Bs + ca * 512;
    }

    const int col = lane & 15;
    const int quad = lane >> 4;
    // loop-invariant swizzled frag offsets (u16 units)
    int aoff[2][4], boff[2][4];
    #pragma unroll
    for (int ks = 0; ks < 2; ++ks)
        #pragma unroll
        for (int i = 0; i < 4; ++i) {
            const int m = wm + i * 16 + col;
            aoff[ks][i] = (m >> 3) * 512 + (m & 7) * 64 +
                          ((((ks << 2) | quad)) ^ (m & 7)) * 8;
            const int n = wn + i * 16 + col;
            boff[ks][i] = (n >> 3) * 512 + (n & 7) * 64 +
                          ((((ks << 2) | quad)) ^ (n & 7)) * 8;
        }

    f32x4 acc[4][4] = {};
    for (int k0 = 0; k0 < K; k0 += 64) {
        __syncthreads();
        #pragma unroll
        for (int c = 0; c < 4; ++c) {
            GLD_LDS(gA[c] + k0, lA[c]);
            GLD_LDS(gB[c] + k0, lB[c]);
        }
        __syncthreads();
        #pragma unroll
        for (int ks = 0; ks < 2; ++ks) {
            bf16x8 a[4], b[4];
            #pragma unroll
            for (int i = 0; i < 4; ++i) a[i] = *(const bf16x8*)(As + aoff[ks][i]);
            #pragma unroll
            for (int j = 0; j < 4; ++j) b[j] = *(const bf16x8*)(Bs + boff[ks][j]);
            #pragma unroll
            for (int i = 0; i < 4; ++i)
                #pragma unroll
                for (int j = 0; j < 4; ++j)
                    acc[i][j] = __builtin_amdgcn_mfma_f32_16x16x32_bf16(
                        a[i], b[j], acc[i][j], 0, 0, 0);
        }
    }

    const int rq = quad * 4;
    if (EPI == 0) {
        #pragma unroll
        for (int i = 0; i < 4; ++i)
            #pragma unroll
            for (int j = 0; j < 4; ++j)
                #pragma unroll
                for (int r = 0; r < 4; ++r)
                    OutF[(size_t)(m0 + wm + i * 16 + rq + r) * N +
                         n0 + wn + j * 16 + col] = acc[i][j][r];
    } else {
        const int sslot = m0 >> 10;   // 0=q 1=k 2=v, block-uniform
        #pragma unroll
        for (int i = 0; i < 4; ++i) {
            const int gm = m0 + wm + i * 16 + rq;
            const int hh = (gm >> 6) & 15;
            const int dbase = gm & 63;
            #pragma unroll
            for (int j = 0; j < 4; ++j) {
                const int gt = n0 + wn + j * 16 + col;
                const int bb = gt >> 11;
                const int t = gt & (T_ - 1);
                const int bh = bb * H_ + hh;
                if (sslot < 2) {
                    const float tf = (float)t;
                    u16x4 ov;
                    #pragma unroll
                    for (int p = 0; p < 2; ++p) {
                        const float ip = (float)((dbase >> 1) + p);
                        const float theta = __expf(-0.2878231366f * ip);
                        const float ang = tf * theta;
                        float sn, cs; __sincosf(ang, &sn, &cs);
                        const float x0 = acc[i][j][2 * p];
                        const float x1 = acc[i][j][2 * p + 1];
                        ov[2 * p]     = f2bf(x0 * cs - x1 * sn);
                        ov[2 * p + 1] = f2bf(x1 * cs + x0 * sn);
                    }
                    u16* dst = (sslot == 0 ? qb : kb) +
                               ((size_t)bh * T_ + t) * D_ + dbase;
                    *(u16x4*)dst = ov;
                } else {
                    #pragma unroll
                    for (int r = 0; r < 4; ++r) {
                        union { _Float16 h; u16 u; } cv;
                        cv.h = (_Float16)acc[i][j][r];
                        vt[((size_t)bh * D_ + dbase + r) * T_ + t] = cv.u;
                    }
                }
            }
        }
    }
}

// ---------------------------------------------------------------------------
// Flash attention v4: 256 thr / 4 waves, 32 q per wave (128-q tile),
// 64-key chunks. S^T via mfma(K, Q); no online max; P f16 via per-wave LDS.
// K/V staged with XOR-swizzled 8-row chunks: GLD fully coalesced
// (K chunks are contiguous 1KB), frag reads bank-clean.
// ---------------------------------------------------------------------------
__global__ __launch_bounds__(256) void attn_mfma(const u16* __restrict__ qb,
                                                 const u16* __restrict__ kb,
                                                 const u16* __restrict__ vtg,
                                                 u16* __restrict__ y) {
    __shared__ u16 Ks[8 * 512];     // [key 64][d 64] swizzled
    __shared__ u16 Vt[8 * 512];     // [d 64][key 64] swizzled
    __shared__ u16 Ps[4][32 * 72];  // per-wave P [32 q][64 key] f16
    const int b = blockIdx.z, h = blockIdx.y;
    const int bh = b * H_ + h;
    const int qt = gridDim.x - 1 - blockIdx.x;  // heavy tiles first
    const int q0 = qt * 128;
    const int tid = threadIdx.x;
    const int lane = tid & 63;
    const int wave = tid >> 6;       // 0..3, owns q rows q0+wave*32..+31
    const int col = lane & 15;
    const int quad = lane >> 4;

    // Q B-fragments: lane holds Q[q = qh*16+col][d = ks*32+quad*8+j]
    const u16* qbase = qb + ((size_t)bh * T_ + q0 + wave * 32) * D_;
    bf16x8 qf[2][2];
    #pragma unroll
    for (int qh = 0; qh < 2; ++qh)
        #pragma unroll
        for (int ks = 0; ks < 2; ++ks)
            qf[qh][ks] = *(const bf16x8*)(qbase + (qh * 16 + col) * D_ +
                                          ks * 32 + quad * 8);

    f32x4 o[2][4] = {};
    float lsum[2] = {0.0f, 0.0f};

    // staging: wave w loads K chunks 2w,2w+1 and V chunks 2w,2w+1
    const int rl = lane >> 3;
    const int sg = ((lane & 7) ^ rl) * 8;
    const u16* kg[2]; const u16* vg[2];
    u16 *lk[2], *lv[2];
    #pragma unroll
    for (int e = 0; e < 2; ++e) {
        const int ca = 2 * wave + e;
        kg[e] = kb + ((size_t)bh * T_ + ca * 8 + rl) * D_ + sg;
        vg[e] = vtg + ((size_t)bh * D_ + ca * 8 + rl) * T_ + sg;
        lk[e] = Ks + ca * 512;
        lv[e] = Vt + ca * 512;
    }
    u16* Pw = &Ps[wave][0];

    // loop-invariant swizzled frag offsets
    int koff[2][4];   // same formula for K (row=key) and V (row=d)
    #pragma unroll
    for (int ks = 0; ks < 2; ++ks)
        #pragma unroll
        for (int n = 0; n < 4; ++n) {
            const int rr = n * 16 + col;
            koff[ks][n] = (rr >> 3) * 512 + (rr & 7) * 64 +
                          ((((ks << 2) | quad)) ^ (rr & 7)) * 8;
        }

    const int nchunks = 2 * qt + 2;
    for (int ci = 0; ci < nchunks; ++ci) {
        const int j0 = ci * 64;
        __syncthreads();   // prior chunk's reads done
        #pragma unroll
        for (int e = 0; e < 2; ++e) {
            GLD_LDS(kg[e] + (size_t)j0 * D_, lk[e]);
            GLD_LDS(vg[e] + j0, lv[e]);
        }
        __syncthreads();   // DMA drained

        // S^T = K Q^T : A = K (m=key), B = Q (n=q)
        f32x4 s[2][4] = {};
        #pragma unroll
        for (int ks = 0; ks < 2; ++ks) {
            #pragma unroll
            for (int n = 0; n < 4; ++n) {
                const bf16x8 kf = *(const bf16x8*)(Ks + koff[ks][n]);
                #pragma unroll
                for (int qh = 0; qh < 2; ++qh)
                    s[qh][n] = __builtin_amdgcn_mfma_f32_16x16x32_bf16(
                        kf, qf[qh][ks], s[qh][n], 0, 0, 0);
            }
        }

        // exp + packed f16 P store; lane: q = qh*16+col, keys n*16+quad*4+r
        const bool diag = (ci >= nchunks - 2);
        #pragma unroll
        for (int qh = 0; qh < 2; ++qh) {
            const int qrow = q0 + wave * 32 + qh * 16 + col;
            #pragma unroll
            for (int n = 0; n < 4; ++n) {
                float p[4];
                #pragma unroll
                for (int r = 0; r < 4; ++r) {
                    const float xv = s[qh][n][r] * 0.1803368801f; // (1/8)*log2e
                    float pv = __builtin_amdgcn_exp2f(fminf(xv, 80.0f));
                    if (diag && (j0 + n * 16 + quad * 4 + r > qrow)) pv = 0.0f;
                    p[r] = pv;
                    lsum[qh] += pv;
                }
                union { fp16x2 h[2]; u32 u[2]; } pk;
                pk.h[0] = __builtin_amdgcn_cvt_pkrtz(p[0], p[1]);
                pk.h[1] = __builtin_amdgcn_cvt_pkrtz(p[2], p[3]);
                *(uint2*)(Pw + (qh * 16 + col) * 72 + n * 16 + quad * 4) =
                    make_uint2(pk.u[0], pk.u[1]);
            }
        }

        // O += P V : A = P (m=q), B = V (n=d)
        #pragma unroll
        for (int ks = 0; ks < 2; ++ks) {
            f16x8 pf[2];
            #pragma unroll
            for (int qh = 0; qh < 2; ++qh)
                pf[qh] = *(const f16x8*)(Pw + (qh * 16 + col) * 72 +
                                         ks * 32 + quad * 8);
            #pragma unroll
            for (int n = 0; n < 4; ++n) {
                const f16x8 vf = *(const f16x8*)(Vt + koff[ks][n]);
                #pragma unroll
                for (int qh = 0; qh < 2; ++qh)
                    o[qh][n] = __builtin_amdgcn_mfma_f32_16x16x32_f16(
                        pf[qh], vf, o[qh][n], 0, 0, 0);
            }
        }
    }

    // reduce row-sums across quads, transpose to output rows, write
    #pragma unroll
    for (int qh = 0; qh < 2; ++qh) {
        float l = lsum[qh];
        l += __shfl_xor(l, 16);
        l += __shfl_xor(l, 32);
        const float inv = 1.0f / l;
        float invr[4];
        #pragma unroll
        for (int r = 0; r < 4; ++r)
            invr[r] = __shfl(inv, quad * 4 + r);   // inv for q = quad*4+r
        #pragma unroll
        for (int r = 0; r < 4; ++r) {
            const int row = q0 + wave * 32 + qh * 16 + quad * 4 + r;
            u16* yp = y + (size_t)(b * T_ + row) * C_ + h * D_;
            #pragma unroll
            for (int n = 0; n < 4; ++n)
                yp[n * 16 + col] = f2bf(o[qh][n][r] * invr[r]);
        }
    }
}

// ---------------------------------------------------------------------------
// Launch
// ---------------------------------------------------------------------------
extern "C" void kernel_launch(void* const* d_in, const int* in_sizes, int n_in,
                              void* d_out, int out_size, void* d_ws, size_t ws_size,
                              hipStream_t stream) {
    const float* x      = (const float*)d_in[0];
    const float* w_qkv  = (const float*)d_in[1];
    const float* w_proj = (const float*)d_in[2];
    float* out = (float*)d_out;

    const int M = B_ * T_;                   // 4096
    u16* xb  = (u16*)d_ws;
    u16* wqb = xb + NX_;
    u16* wpb = wqb + NWQ_;
    u16* qb  = wpb + NWP_;
    u16* kb  = qb + NX_;
    u16* vt  = kb + NX_;     // f16 (b,h,d,t)
    u16* yb  = vt + NX_;     // bf16 (b,t,h,d)

    cast_all<<<(NX_ + NWQ_ + NWP_) / 1024, 256, 0, stream>>>(x, w_qkv, w_proj, xb);

    // qkv^T = w_qkv @ x^T, fused RoPE + split into qb/kb (bf16), vt (f16)
    gemm64<1><<<dim3(M / 128, 3 * C_ / 128), 256, 0, stream>>>(
        wqb, xb, nullptr, qb, kb, vt, 3 * C_, M, C_);

    attn_mfma<<<dim3(T_ / 128, H_, B_), 256, 0, stream>>>(qb, kb, vt, yb);

    // out = y @ w_proj^T -> fp32
    gemm64<0><<<dim3(C_ / 128, M / 128), 256, 0, stream>>>(
        yb, wpb, out, nullptr, nullptr, nullptr, M, C_, C_);
}

// Round 9
// 190.035 us; speedup vs baseline: 1.3037x; 1.0882x over previous
//
#include <hip/hip_runtime.h>
#include <math.h>

#define B_ 2
#define T_ 2048
#define C_ 1024
#define H_ 16
#define D_ 64
#define NX_ 4194304
#define NWQ_ 3145728
#define NWP_ 1048576

typedef unsigned short u16;
typedef unsigned int u32;
typedef __bf16 bf16x8 __attribute__((ext_vector_type(8)));
typedef _Float16 f16x8 __attribute__((ext_vector_type(8)));
typedef __fp16 fp16x2 __attribute__((ext_vector_type(2)));
typedef float f32x4 __attribute__((ext_vector_type(4)));
typedef u16 u16x4 __attribute__((ext_vector_type(4)));

__device__ __forceinline__ u16 f2bf(float f) {
    union { float f; u32 u; } v; v.f = f;
    u32 r = v.u + 0x7fffu + ((v.u >> 16) & 1u);   // RNE
    return (u16)(r >> 16);
}

#define GLD_LDS(g, l) \
    __builtin_amdgcn_global_load_lds( \
        (const __attribute__((address_space(1))) u32*)(const void*)(g), \
        (__attribute__((address_space(3))) u32*)(void*)(l), 16, 0, 0)

// ---------------------------------------------------------------------------
// fused cast of all three fp32 inputs -> one contiguous bf16 region
// ---------------------------------------------------------------------------
__global__ __launch_bounds__(256) void cast_all(const float* __restrict__ x,
                                                const float* __restrict__ wq,
                                                const float* __restrict__ wp,
                                                u16* __restrict__ out) {
    const int i = (blockIdx.x * 256 + threadIdx.x) * 4;
    const float* src;
    int off;
    if (i < NX_) { src = x; off = i; }
    else if (i < NX_ + NWQ_) { src = wq; off = i - NX_; }
    else { src = wp; off = i - NX_ - NWQ_; }
    float4 v = *(const float4*)(src + off);
    u16x4 o;
    o.x = f2bf(v.x); o.y = f2bf(v.y); o.z = f2bf(v.z); o.w = f2bf(v.w);
    *(u16x4*)(out + i) = o;
}

// ---------------------------------------------------------------------------
// bf16 GEMM, 128x128 tile, BK=64, XOR-swizzled LDS (coalesced GLD +
// conflict-free frag reads). Out = A[M][K] @ Bm[N][K]^T.
// EPI 0: fp32 row-major output. EPI 1: fused RoPE + per-head q/k/v split
// (round-7 numerics: NO prescale on q).
// ---------------------------------------------------------------------------
template <int EPI>
__global__ __launch_bounds__(256) void gemm64(const u16* __restrict__ A,
                                              const u16* __restrict__ Bm,
                                              float* __restrict__ OutF,
                                              u16* __restrict__ qb,
                                              u16* __restrict__ kb,
                                              u16* __restrict__ vt,
                                              int M, int N, int K) {
    __shared__ u16 As[128 * 64];
    __shared__ u16 Bs[128 * 64];
    const int tid = threadIdx.x;
    const int lane = tid & 63;
    const int wave = tid >> 6;
    const int wm = (wave >> 1) * 64;
    const int wn = (wave & 1) * 64;
    const int m0 = blockIdx.y * 128;
    const int n0 = blockIdx.x * 128;

    const int rl = lane >> 3;
    const int sg = ((lane & 7) ^ rl) * 8;
    const u16* gA[4]; const u16* gB[4];
    u16 *lA[4], *lB[4];
    #pragma unroll
    for (int c = 0; c < 4; ++c) {
        const int ca = wave * 4 + c;
        gA[c] = A + (size_t)(m0 + ca * 8 + rl) * K + sg;
        gB[c] = Bm + (size_t)(n0 + ca * 8 + rl) * K + sg;
        lA[c] = As + ca * 512;
        lB[c] = Bs + ca * 512;
    }

    const int col = lane & 15;
    const int quad = lane >> 4;
    int aoff[2][4], boff[2][4];
    #pragma unroll
    for (int ks = 0; ks < 2; ++ks)
        #pragma unroll
        for (int i = 0; i < 4; ++i) {
            const int m = wm + i * 16 + col;
            aoff[ks][i] = (m >> 3) * 512 + (m & 7) * 64 +
                          ((((ks << 2) | quad)) ^ (m & 7)) * 8;
            const int n = wn + i * 16 + col;
            boff[ks][i] = (n >> 3) * 512 + (n & 7) * 64 +
                          ((((ks << 2) | quad)) ^ (n & 7)) * 8;
        }

    f32x4 acc[4][4] = {};
    for (int k0 = 0; k0 < K; k0 += 64) {
        __syncthreads();
        #pragma unroll
        for (int c = 0; c < 4; ++c) {
            GLD_LDS(gA[c] + k0, lA[c]);
            GLD_LDS(gB[c] + k0, lB[c]);
        }
        __syncthreads();
        #pragma unroll
        for (int ks = 0; ks < 2; ++ks) {
            bf16x8 a[4], b[4];
            #pragma unroll
            for (int i = 0; i < 4; ++i) a[i] = *(const bf16x8*)(As + aoff[ks][i]);
            #pragma unroll
            for (int j = 0; j < 4; ++j) b[j] = *(const bf16x8*)(Bs + boff[ks][j]);
            #pragma unroll
            for (int i = 0; i < 4; ++i)
                #pragma unroll
                for (int j = 0; j < 4; ++j)
                    acc[i][j] = __builtin_amdgcn_mfma_f32_16x16x32_bf16(
                        a[i], b[j], acc[i][j], 0, 0, 0);
        }
    }

    const int rq = quad * 4;
    if (EPI == 0) {
        #pragma unroll
        for (int i = 0; i < 4; ++i)
            #pragma unroll
            for (int j = 0; j < 4; ++j)
                #pragma unroll
                for (int r = 0; r < 4; ++r)
                    OutF[(size_t)(m0 + wm + i * 16 + rq + r) * N +
                         n0 + wn + j * 16 + col] = acc[i][j][r];
    } else {
        const int sslot = m0 >> 10;   // 0=q 1=k 2=v, block-uniform
        #pragma unroll
        for (int i = 0; i < 4; ++i) {
            const int gm = m0 + wm + i * 16 + rq;
            const int hh = (gm >> 6) & 15;
            const int dbase = gm & 63;
            #pragma unroll
            for (int j = 0; j < 4; ++j) {
                const int gt = n0 + wn + j * 16 + col;
                const int bb = gt >> 11;
                const int t = gt & (T_ - 1);
                const int bh = bb * H_ + hh;
                if (sslot < 2) {
                    const float tf = (float)t;
                    u16x4 ov;
                    #pragma unroll
                    for (int p = 0; p < 2; ++p) {
                        const float ip = (float)((dbase >> 1) + p);
                        const float theta = __expf(-0.2878231366f * ip);
                        const float ang = tf * theta;
                        float sn, cs; __sincosf(ang, &sn, &cs);
                        const float x0 = acc[i][j][2 * p];
                        const float x1 = acc[i][j][2 * p + 1];
                        ov[2 * p]     = f2bf(x0 * cs - x1 * sn);
                        ov[2 * p + 1] = f2bf(x1 * cs + x0 * sn);
                    }
                    u16* dst = (sslot == 0 ? qb : kb) +
                               ((size_t)bh * T_ + t) * D_ + dbase;
                    *(u16x4*)dst = ov;
                } else {
                    #pragma unroll
                    for (int r = 0; r < 4; ++r) {
                        union { _Float16 h; u16 u; } cv;
                        cv.h = (_Float16)acc[i][j][r];
                        vt[((size_t)bh * D_ + dbase + r) * T_ + t] = cv.u;
                    }
                }
            }
        }
    }
}

// ---------------------------------------------------------------------------
// Flash attention v6: round-7 numerics (fp32 scale+clamp+exp, fp32 scalar
// lsum + end shuffles) + round-8 structure (dbuf K/V, ONE barrier per chunk,
// heavy/light paired 1D grid). 256 thr / 4 waves x 32 q, 64-key chunks.
// ---------------------------------------------------------------------------
__global__ __launch_bounds__(256) void attn_mfma(const u16* __restrict__ qb,
                                                 const u16* __restrict__ kb,
                                                 const u16* __restrict__ vtg,
                                                 u16* __restrict__ y) {
    __shared__ u16 Ks[2][8 * 512];  // [buf][key 64][d 64] swizzled
    __shared__ u16 Vt[2][8 * 512];  // [buf][d 64][key 64] swizzled
    __shared__ u16 Ps[4][32 * 72];  // per-wave P [32 q][64 key] f16
    const int id = blockIdx.x;      // 0..511
    const int qt = (id < 256) ? (15 - (id >> 5)) : ((id - 256) >> 5);
    const int bh = id & 31;
    const int b = bh >> 4, h = bh & 15;
    const int q0 = qt * 128;
    const int tid = threadIdx.x;
    const int lane = tid & 63;
    const int wave = tid >> 6;      // 0..3, owns q rows q0+wave*32..+31
    const int col = lane & 15;
    const int quad = lane >> 4;

    // Q B-fragments: lane holds Q[q=qh*16+col][d=ks*32+quad*8+j]
    const u16* qbase = qb + ((size_t)bh * T_ + q0 + wave * 32) * D_;
    bf16x8 qf[2][2];
    #pragma unroll
    for (int qh = 0; qh < 2; ++qh)
        #pragma unroll
        for (int ks = 0; ks < 2; ++ks)
            qf[qh][ks] = *(const bf16x8*)(qbase + (qh * 16 + col) * D_ +
                                          ks * 32 + quad * 8);

    f32x4 o[2][4] = {};
    float lsum[2] = {0.0f, 0.0f};

    // staging: wave w loads K chunks 2w,2w+1 and V chunks 2w,2w+1
    const int rl = lane >> 3;
    const int sg = ((lane & 7) ^ rl) * 8;
    const u16* kg[2]; const u16* vg[2];
    int lco[2];
    #pragma unroll
    for (int e = 0; e < 2; ++e) {
        const int ca = 2 * wave + e;
        kg[e] = kb + ((size_t)bh * T_ + ca * 8 + rl) * D_ + sg;
        vg[e] = vtg + ((size_t)bh * D_ + ca * 8 + rl) * T_ + sg;
        lco[e] = ca * 512;
    }
    u16* Pw = &Ps[wave][0];

    int koff[2][4];   // swizzled frag offsets (K: row=key; V: row=d)
    #pragma unroll
    for (int ks = 0; ks < 2; ++ks)
        #pragma unroll
        for (int n = 0; n < 4; ++n) {
            const int rr = n * 16 + col;
            koff[ks][n] = (rr >> 3) * 512 + (rr & 7) * 64 +
                          ((((ks << 2) | quad)) ^ (rr & 7)) * 8;
        }

    const int nchunks = 2 * qt + 2;
    // prologue: chunk 0 into buf 0
    #pragma unroll
    for (int e = 0; e < 2; ++e) {
        GLD_LDS(kg[e], &Ks[0][lco[e]]);
        GLD_LDS(vg[e], &Vt[0][lco[e]]);
    }

    for (int ci = 0; ci < nchunks; ++ci) {
        const int buf = ci & 1;
        const int j0 = ci * 64;
        __syncthreads();   // drains DMA(chunk ci); prior reads of buf^1 done
        if (ci + 1 < nchunks) {
            const size_t j1 = (size_t)(ci + 1) * 64;
            #pragma unroll
            for (int e = 0; e < 2; ++e) {
                GLD_LDS(kg[e] + j1 * D_, &Ks[buf ^ 1][lco[e]]);
                GLD_LDS(vg[e] + j1, &Vt[buf ^ 1][lco[e]]);
            }
        }

        // S^T = K Q^T : A = K (m=key), B = Q (n=q)
        f32x4 s[2][4] = {};
        #pragma unroll
        for (int ks = 0; ks < 2; ++ks) {
            #pragma unroll
            for (int n = 0; n < 4; ++n) {
                const bf16x8 kf = *(const bf16x8*)(&Ks[buf][koff[ks][n]]);
                #pragma unroll
                for (int qh = 0; qh < 2; ++qh)
                    s[qh][n] = __builtin_amdgcn_mfma_f32_16x16x32_bf16(
                        kf, qf[qh][ks], s[qh][n], 0, 0, 0);
            }
        }

        // P = exp(S/8), causal-masked on diagonal chunks (round-7 numerics)
        const bool diag = (ci >= nchunks - 2);
        #pragma unroll
        for (int qh = 0; qh < 2; ++qh) {
            const int qrow = q0 + wave * 32 + qh * 16 + col;
            #pragma unroll
            for (int n = 0; n < 4; ++n) {
                float p[4];
                #pragma unroll
                for (int r = 0; r < 4; ++r) {
                    const float xv = s[qh][n][r] * 0.1803368801f; // (1/8)*log2e
                    float pv = __builtin_amdgcn_exp2f(fminf(xv, 80.0f));
                    if (diag && (j0 + n * 16 + quad * 4 + r > qrow)) pv = 0.0f;
                    p[r] = pv;
                    lsum[qh] += pv;
                }
                union { fp16x2 h[2]; u32 u[2]; } pk;
                pk.h[0] = __builtin_amdgcn_cvt_pkrtz(p[0], p[1]);
                pk.h[1] = __builtin_amdgcn_cvt_pkrtz(p[2], p[3]);
                *(uint2*)(Pw + (qh * 16 + col) * 72 + n * 16 + quad * 4) =
                    make_uint2(pk.u[0], pk.u[1]);
            }
        }

        // O += P V : A = P (m=q), B = V (n=d)
        #pragma unroll
        for (int ks = 0; ks < 2; ++ks) {
            f16x8 pf[2];
            #pragma unroll
            for (int qh = 0; qh < 2; ++qh)
                pf[qh] = *(const f16x8*)(Pw + (qh * 16 + col) * 72 +
                                         ks * 32 + quad * 8);
            #pragma unroll
            for (int n = 0; n < 4; ++n) {
                const f16x8 vf = *(const f16x8*)(&Vt[buf][koff[ks][n]]);
                #pragma unroll
                for (int qh = 0; qh < 2; ++qh)
                    o[qh][n] = __builtin_amdgcn_mfma_f32_16x16x32_f16(
                        pf[qh], vf, o[qh][n], 0, 0, 0);
            }
        }
    }

    // reduce row-sums across quads, transpose to output rows, write
    #pragma unroll
    for (int qh = 0; qh < 2; ++qh) {
        float l = lsum[qh];
        l += __shfl_xor(l, 16);
        l += __shfl_xor(l, 32);
        const float inv = 1.0f / l;
        float invr[4];
        #pragma unroll
        for (int r = 0; r < 4; ++r)
            invr[r] = __shfl(inv, quad * 4 + r);   // inv for q = quad*4+r
        #pragma unroll
        for (int r = 0; r < 4; ++r) {
            const int row = q0 + wave * 32 + qh * 16 + quad * 4 + r;
            u16* yp = y + (size_t)(b * T_ + row) * C_ + h * D_;
            #pragma unroll
            for (int n = 0; n < 4; ++n)
                yp[n * 16 + col] = f2bf(o[qh][n][r] * invr[r]);
        }
    }
}

// ---------------------------------------------------------------------------
// Launch
// ---------------------------------------------------------------------------
extern "C" void kernel_launch(void* const* d_in, const int* in_sizes, int n_in,
                              void* d_out, int out_size, void* d_ws, size_t ws_size,
                              hipStream_t stream) {
    const float* x      = (const float*)d_in[0];
    const float* w_qkv  = (const float*)d_in[1];
    const float* w_proj = (const float*)d_in[2];
    float* out = (float*)d_out;

    const int M = B_ * T_;                   // 4096
    u16* xb  = (u16*)d_ws;
    u16* wqb = xb + NX_;
    u16* wpb = wqb + NWQ_;
    u16* qb  = wpb + NWP_;
    u16* kb  = qb + NX_;
    u16* vt  = kb + NX_;     // f16 (b,h,d,t)
    u16* yb  = vt + NX_;     // bf16 (b,t,h,d)

    cast_all<<<(NX_ + NWQ_ + NWP_) / 1024, 256, 0, stream>>>(x, w_qkv, w_proj, xb);

    // qkv^T = w_qkv @ x^T, fused RoPE + split into qb/kb (bf16), vt (f16)
    gemm64<1><<<dim3(M / 128, 3 * C_ / 128), 256, 0, stream>>>(
        wqb, xb, nullptr, qb, kb, vt, 3 * C_, M, C_);

    attn_mfma<<<512, 256, 0, stream>>>(qb, kb, vt, yb);

    // out = y @ w_proj^T -> fp32
    gemm64<0><<<dim3(C_ / 128, M / 128), 256, 0, stream>>>(
        yb, wpb, out, nullptr, nullptr, nullptr, M, C_, C_);
}

// Round 10
// 179.351 us; speedup vs baseline: 1.3813x; 1.0596x over previous
//
#include <hip/hip_runtime.h>
#include <math.h>

#define B_ 2
#define T_ 2048
#define C_ 1024
#define H_ 16
#define D_ 64
#define NX_ 4194304
#define NWQ_ 3145728
#define NWP_ 1048576

typedef unsigned short u16;
typedef unsigned int u32;
typedef __bf16 bf16x8 __attribute__((ext_vector_type(8)));
typedef _Float16 f16x8 __attribute__((ext_vector_type(8)));
typedef __fp16 fp16x2 __attribute__((ext_vector_type(2)));
typedef float f32x4 __attribute__((ext_vector_type(4)));
typedef u16 u16x4 __attribute__((ext_vector_type(4)));

__device__ __forceinline__ u16 f2bf(float f) {
    union { float f; u32 u; } v; v.f = f;
    u32 r = v.u + 0x7fffu + ((v.u >> 16) & 1u);   // RNE
    return (u16)(r >> 16);
}

#define GLD_LDS(g, l) \
    __builtin_amdgcn_global_load_lds( \
        (const __attribute__((address_space(1))) u32*)(const void*)(g), \
        (__attribute__((address_space(3))) u32*)(void*)(l), 16, 0, 0)

// ---------------------------------------------------------------------------
// fused cast of the three fp32 inputs -> bf16, plus RoPE cos/sin table
// tab[(t*32+i)*2] = cos(t*theta_i), +1 = sin  (theta_i = 10000^(-i/32))
// ---------------------------------------------------------------------------
__global__ __launch_bounds__(256) void cast_all(const float* __restrict__ x,
                                                const float* __restrict__ wq,
                                                const float* __restrict__ wp,
                                                u16* __restrict__ out,
                                                float* __restrict__ tab) {
    const int bid = blockIdx.x;
    if (bid >= 8192) {   // RoPE table: 65536 pairs, 2 pairs/thread
        const int k = (bid - 8192) * 256 + threadIdx.x;
        #pragma unroll
        for (int e = 0; e < 2; ++e) {
            const int pidx = 2 * k + e;
            const int t = pidx >> 5, i = pidx & 31;
            const float theta = __expf(-0.2878231366f * (float)i);
            float sn, cs;
            __sincosf((float)t * theta, &sn, &cs);
            *(float2*)(tab + pidx * 2) = make_float2(cs, sn);
        }
        return;
    }
    const int i = (bid * 256 + threadIdx.x) * 4;
    const float* src;
    int off;
    if (i < NX_) { src = x; off = i; }
    else if (i < NX_ + NWQ_) { src = wq; off = i - NX_; }
    else { src = wp; off = i - NX_ - NWQ_; }
    float4 v = *(const float4*)(src + off);
    u16x4 o;
    o.x = f2bf(v.x); o.y = f2bf(v.y); o.z = f2bf(v.z); o.w = f2bf(v.w);
    *(u16x4*)(out + i) = o;
}

// ---------------------------------------------------------------------------
// bf16 GEMM, 128x128 tile, BK=64, XOR-swizzled LDS (coalesced GLD +
// conflict-free frag reads). Out = A[M][K] @ Bm[N][K]^T.
// EPI 0: fp32 row-major output. EPI 1: fused RoPE (table-driven) + per-head
// q/k/v split (no q prescale — round-9 numerics).
// ---------------------------------------------------------------------------
template <int EPI>
__global__ __launch_bounds__(256) void gemm64(const u16* __restrict__ A,
                                              const u16* __restrict__ Bm,
                                              float* __restrict__ OutF,
                                              u16* __restrict__ qb,
                                              u16* __restrict__ kb,
                                              u16* __restrict__ vt,
                                              const float* __restrict__ tab,
                                              int M, int N, int K) {
    __shared__ u16 As[128 * 64];
    __shared__ u16 Bs[128 * 64];
    const int tid = threadIdx.x;
    const int lane = tid & 63;
    const int wave = tid >> 6;
    const int wm = (wave >> 1) * 64;
    const int wn = (wave & 1) * 64;
    const int m0 = blockIdx.y * 128;
    const int n0 = blockIdx.x * 128;

    const int rl = lane >> 3;
    const int sg = ((lane & 7) ^ rl) * 8;
    const u16* gA[4]; const u16* gB[4];
    u16 *lA[4], *lB[4];
    #pragma unroll
    for (int c = 0; c < 4; ++c) {
        const int ca = wave * 4 + c;
        gA[c] = A + (size_t)(m0 + ca * 8 + rl) * K + sg;
        gB[c] = Bm + (size_t)(n0 + ca * 8 + rl) * K + sg;
        lA[c] = As + ca * 512;
        lB[c] = Bs + ca * 512;
    }

    const int col = lane & 15;
    const int quad = lane >> 4;
    int aoff[2][4], boff[2][4];
    #pragma unroll
    for (int ks = 0; ks < 2; ++ks)
        #pragma unroll
        for (int i = 0; i < 4; ++i) {
            const int m = wm + i * 16 + col;
            aoff[ks][i] = (m >> 3) * 512 + (m & 7) * 64 +
                          ((((ks << 2) | quad)) ^ (m & 7)) * 8;
            const int n = wn + i * 16 + col;
            boff[ks][i] = (n >> 3) * 512 + (n & 7) * 64 +
                          ((((ks << 2) | quad)) ^ (n & 7)) * 8;
        }

    f32x4 acc[4][4] = {};
    for (int k0 = 0; k0 < K; k0 += 64) {
        __syncthreads();
        #pragma unroll
        for (int c = 0; c < 4; ++c) {
            GLD_LDS(gA[c] + k0, lA[c]);
            GLD_LDS(gB[c] + k0, lB[c]);
        }
        __syncthreads();
        #pragma unroll
        for (int ks = 0; ks < 2; ++ks) {
            bf16x8 a[4], b[4];
            #pragma unroll
            for (int i = 0; i < 4; ++i) a[i] = *(const bf16x8*)(As + aoff[ks][i]);
            #pragma unroll
            for (int j = 0; j < 4; ++j) b[j] = *(const bf16x8*)(Bs + boff[ks][j]);
            #pragma unroll
            for (int i = 0; i < 4; ++i)
                #pragma unroll
                for (int j = 0; j < 4; ++j)
                    acc[i][j] = __builtin_amdgcn_mfma_f32_16x16x32_bf16(
                        a[i], b[j], acc[i][j], 0, 0, 0);
        }
    }

    const int rq = quad * 4;
    if (EPI == 0) {
        #pragma unroll
        for (int i = 0; i < 4; ++i)
            #pragma unroll
            for (int j = 0; j < 4; ++j)
                #pragma unroll
                for (int r = 0; r < 4; ++r)
                    OutF[(size_t)(m0 + wm + i * 16 + rq + r) * N +
                         n0 + wn + j * 16 + col] = acc[i][j][r];
    } else {
        const int sslot = m0 >> 10;   // 0=q 1=k 2=v, block-uniform
        #pragma unroll
        for (int i = 0; i < 4; ++i) {
            const int gm = m0 + wm + i * 16 + rq;
            const int hh = (gm >> 6) & 15;
            const int dbase = gm & 63;
            #pragma unroll
            for (int j = 0; j < 4; ++j) {
                const int gt = n0 + wn + j * 16 + col;
                const int bb = gt >> 11;
                const int t = gt & (T_ - 1);
                const int bh = bb * H_ + hh;
                if (sslot < 2) {
                    // table: (cos,sin) for pairs ip=dbase/2 and ip+1
                    const float4 cs4 = *(const float4*)(tab + t * 64 + dbase);
                    u16x4 ov;
                    ov[0] = f2bf(acc[i][j][0] * cs4.x - acc[i][j][1] * cs4.y);
                    ov[1] = f2bf(acc[i][j][1] * cs4.x + acc[i][j][0] * cs4.y);
                    ov[2] = f2bf(acc[i][j][2] * cs4.z - acc[i][j][3] * cs4.w);
                    ov[3] = f2bf(acc[i][j][3] * cs4.z + acc[i][j][2] * cs4.w);
                    u16* dst = (sslot == 0 ? qb : kb) +
                               ((size_t)bh * T_ + t) * D_ + dbase;
                    *(u16x4*)dst = ov;
                } else {
                    #pragma unroll
                    for (int r = 0; r < 4; ++r) {
                        union { _Float16 h; u16 u; } cv;
                        cv.h = (_Float16)acc[i][j][r];
                        vt[((size_t)bh * D_ + dbase + r) * T_ + t] = cv.u;
                    }
                }
            }
        }
    }
}

// ---------------------------------------------------------------------------
// Flash attention v7: 256 thr / 4 waves x 16 q (64-q tile), 64-key chunks,
// dbuf K/V one barrier per chunk, heavy/light paired 1D grid (1024 blocks).
// P never touches LDS: C/D -> A-operand via in-wave shuffles.
// LDS = 32 KB -> 4 blocks/CU (16 waves/CU).
// ---------------------------------------------------------------------------
__global__ __launch_bounds__(256) void attn_mfma(const u16* __restrict__ qb,
                                                 const u16* __restrict__ kb,
                                                 const u16* __restrict__ vtg,
                                                 u16* __restrict__ y) {
    __shared__ u16 Ks[2][8 * 512];  // [buf][key 64][d 64] swizzled
    __shared__ u16 Vt[2][8 * 512];  // [buf][d 64][key 64] swizzled
    const int id = blockIdx.x;      // 0..1023
    const int qt = (id < 512) ? (31 - (id >> 5)) : ((id - 512) >> 5);
    const int bh = id & 31;
    const int b = bh >> 4, h = bh & 15;
    const int q0 = qt * 64;
    const int tid = threadIdx.x;
    const int lane = tid & 63;
    const int wave = tid >> 6;      // 0..3, owns q rows q0+wave*16..+15
    const int col = lane & 15;
    const int quad = lane >> 4;

    // Q B-fragments: lane holds Q[q=col][d=ks*32+quad*8+j]
    const u16* qbase = qb + ((size_t)bh * T_ + q0 + wave * 16) * D_;
    bf16x8 qf[2];
    #pragma unroll
    for (int ks = 0; ks < 2; ++ks)
        qf[ks] = *(const bf16x8*)(qbase + col * D_ + ks * 32 + quad * 8);

    f32x4 o[4] = {};
    float lsum = 0.0f;

    // staging: wave w loads K chunks 2w,2w+1 and V chunks 2w,2w+1
    const int rl = lane >> 3;
    const int sg = ((lane & 7) ^ rl) * 8;
    const u16* kg[2]; const u16* vg[2];
    int lco[2];
    #pragma unroll
    for (int e = 0; e < 2; ++e) {
        const int ca = 2 * wave + e;
        kg[e] = kb + ((size_t)bh * T_ + ca * 8 + rl) * D_ + sg;
        vg[e] = vtg + ((size_t)bh * D_ + ca * 8 + rl) * T_ + sg;
        lco[e] = ca * 512;
    }

    int koff[2][4];   // swizzled frag offsets (K: row=key; V: row=d)
    #pragma unroll
    for (int ks = 0; ks < 2; ++ks)
        #pragma unroll
        for (int n = 0; n < 4; ++n) {
            const int rr = n * 16 + col;
            koff[ks][n] = (rr >> 3) * 512 + (rr & 7) * 64 +
                          ((((ks << 2) | quad)) ^ (rr & 7)) * 8;
        }

    // shuffle sources for P C/D -> A-operand transform
    const int srcA = col + ((quad & 1) << 5);   // lane of q-group q' = 2*(quad&1)
    const int srcB = srcA + 16;                 // q' + 1
    const bool hi = (quad >> 1) != 0;           // use n = 2ks+1 ?
    const int qrow = q0 + wave * 16 + col;

    const int nchunks = qt + 1;
    // prologue: chunk 0 into buf 0
    #pragma unroll
    for (int e = 0; e < 2; ++e) {
        GLD_LDS(kg[e], &Ks[0][lco[e]]);
        GLD_LDS(vg[e], &Vt[0][lco[e]]);
    }

    for (int ci = 0; ci < nchunks; ++ci) {
        const int buf = ci & 1;
        const int j0 = ci * 64;
        __syncthreads();   // drains DMA(chunk ci); prior reads of buf^1 done
        if (ci + 1 < nchunks) {
            const size_t j1 = (size_t)(ci + 1) * 64;
            #pragma unroll
            for (int e = 0; e < 2; ++e) {
                GLD_LDS(kg[e] + j1 * D_, &Ks[buf ^ 1][lco[e]]);
                GLD_LDS(vg[e] + j1, &Vt[buf ^ 1][lco[e]]);
            }
        }

        // S^T = K Q^T : A = K (m=key), B = Q (n=q)
        f32x4 s[4] = {};
        #pragma unroll
        for (int ks = 0; ks < 2; ++ks)
            #pragma unroll
            for (int n = 0; n < 4; ++n) {
                const bf16x8 kf = *(const bf16x8*)(&Ks[buf][koff[ks][n]]);
                s[n] = __builtin_amdgcn_mfma_f32_16x16x32_bf16(
                    kf, qf[ks], s[n], 0, 0, 0);
            }

        // P = exp2(S * scale*log2e), masked on diagonal chunk; pack f16
        const bool diag = (ci == nchunks - 1);
        u32 pk[4][2];
        #pragma unroll
        for (int n = 0; n < 4; ++n) {
            float p[4];
            #pragma unroll
            for (int r = 0; r < 4; ++r) {
                float pv = __builtin_amdgcn_exp2f(s[n][r] * 0.1803368801f);
                if (diag && (j0 + n * 16 + quad * 4 + r > qrow)) pv = 0.0f;
                p[r] = pv;
                lsum += pv;
            }
            union { fp16x2 h; u32 u; } k0, k1;
            k0.h = __builtin_amdgcn_cvt_pkrtz(p[0], p[1]);
            k1.h = __builtin_amdgcn_cvt_pkrtz(p[2], p[3]);
            pk[n][0] = k0.u;
            pk[n][1] = k1.u;
        }

        // O += P V : A-frag of P built by in-wave shuffles
        // dest (col,quad) j-th key = ks*32+quad*8+j -> src lane col+16*q',
        // q' = 2(quad&1)+(j>>2), n = 2ks+(quad>>1), r = j&3
        #pragma unroll
        for (int ks = 0; ks < 2; ++ks) {
            const int nl = 2 * ks, nh = nl + 1;
            const u32 w0a = __shfl(pk[nl][0], srcA), w0b = __shfl(pk[nh][0], srcA);
            const u32 w1a = __shfl(pk[nl][1], srcA), w1b = __shfl(pk[nh][1], srcA);
            const u32 w2a = __shfl(pk[nl][0], srcB), w2b = __shfl(pk[nh][0], srcB);
            const u32 w3a = __shfl(pk[nl][1], srcB), w3b = __shfl(pk[nh][1], srcB);
            union { u32 u[4]; f16x8 v; } af;
            af.u[0] = hi ? w0b : w0a;
            af.u[1] = hi ? w1b : w1a;
            af.u[2] = hi ? w2b : w2a;
            af.u[3] = hi ? w3b : w3a;
            #pragma unroll
            for (int n = 0; n < 4; ++n) {
                const f16x8 vf = *(const f16x8*)(&Vt[buf][koff[ks][n]]);
                o[n] = __builtin_amdgcn_mfma_f32_16x16x32_f16(
                    af.v, vf, o[n], 0, 0, 0);
            }
        }
    }

    // reduce row-sums across quads, transpose to output rows, write
    float l = lsum;
    l += __shfl_xor(l, 16);
    l += __shfl_xor(l, 32);
    const float inv = 1.0f / l;
    float invr[4];
    #pragma unroll
    for (int r = 0; r < 4; ++r)
        invr[r] = __shfl(inv, quad * 4 + r);   // inv for q = quad*4+r
    #pragma unroll
    for (int r = 0; r < 4; ++r) {
        const int row = q0 + wave * 16 + quad * 4 + r;
        u16* yp = y + (size_t)(b * T_ + row) * C_ + h * D_;
        #pragma unroll
        for (int n = 0; n < 4; ++n)
            yp[n * 16 + col] = f2bf(o[n][r] * invr[r]);
    }
}

// ---------------------------------------------------------------------------
// Launch
// ---------------------------------------------------------------------------
extern "C" void kernel_launch(void* const* d_in, const int* in_sizes, int n_in,
                              void* d_out, int out_size, void* d_ws, size_t ws_size,
                              hipStream_t stream) {
    const float* x      = (const float*)d_in[0];
    const float* w_qkv  = (const float*)d_in[1];
    const float* w_proj = (const float*)d_in[2];
    float* out = (float*)d_out;

    const int M = B_ * T_;                   // 4096
    u16* xb  = (u16*)d_ws;
    u16* wqb = xb + NX_;
    u16* wpb = wqb + NWQ_;
    u16* qb  = wpb + NWP_;
    u16* kb  = qb + NX_;
    u16* vt  = kb + NX_;     // f16 (b,h,d,t)
    u16* yb  = vt + NX_;     // bf16 (b,t,h,d)
    float* tab = (float*)(yb + NX_);   // RoPE table, 512 KB

    cast_all<<<8192 + 128, 256, 0, stream>>>(x, w_qkv, w_proj, xb, tab);

    // qkv^T = w_qkv @ x^T, fused RoPE + split into qb/kb (bf16), vt (f16)
    gemm64<1><<<dim3(M / 128, 3 * C_ / 128), 256, 0, stream>>>(
        wqb, xb, nullptr, qb, kb, vt, tab, 3 * C_, M, C_);

    attn_mfma<<<1024, 256, 0, stream>>>(qb, kb, vt, yb);

    // out = y @ w_proj^T -> fp32
    gemm64<0><<<dim3(C_ / 128, M / 128), 256, 0, stream>>>(
        yb, wpb, out, nullptr, nullptr, nullptr, nullptr, M, C_, C_);
}